// Round 16
// baseline (142.664 us; speedup 1.0000x reference)
//
#include <hip/hip_runtime.h>
#include <hip/hip_bf16.h>
#include <math.h>

typedef unsigned short u16;
typedef __attribute__((ext_vector_type(8))) __bf16 bf16x8;
typedef __attribute__((ext_vector_type(4))) float f32x4;

static __device__ __forceinline__ u16 f2bf(float f) {
    unsigned int u = __builtin_bit_cast(unsigned int, f);
    u += 0x7fffu + ((u >> 16) & 1u);   // RNE
    return (u16)(u >> 16);
}

// ---------------- Fused prep: LN + w_qkv transpose + w_out transpose ----------
// blocks [0,4096)    : LayerNorm row -> xn bf16
// blocks [4096,4864) : wqkv fp32 [1024][3072] -> wqkvT bf16 [3072][1024]
// blocks [4864,5120) : wout fp32 [1024][1024] -> woutT bf16 [1024][1024]
__global__ __launch_bounds__(256) void prep_kernel(
    const float* __restrict__ x, const float* __restrict__ g,
    const float* __restrict__ bta, u16* __restrict__ xn,
    const float* __restrict__ wqkv, u16* __restrict__ wqkvT,
    const float* __restrict__ wout, u16* __restrict__ woutT)
{
    const int bid = blockIdx.x;
    const int tid = threadIdx.x;
    if (bid < 4096) {
        const int row = bid;
        const float4 v = *(const float4*)&x[(size_t)row * 1024 + tid * 4];
        float s  = v.x + v.y + v.z + v.w;
        float s2 = v.x * v.x + v.y * v.y + v.z * v.z + v.w * v.w;
        #pragma unroll
        for (int off = 32; off; off >>= 1) {
            s  += __shfl_xor(s,  off);
            s2 += __shfl_xor(s2, off);
        }
        __shared__ float red[8];
        if ((tid & 63) == 0) { red[tid >> 6] = s; red[4 + (tid >> 6)] = s2; }
        __syncthreads();
        s  = red[0] + red[1] + red[2] + red[3];
        s2 = red[4] + red[5] + red[6] + red[7];
        const float mean = s * (1.0f / 1024.0f);
        const float var  = s2 * (1.0f / 1024.0f) - mean * mean;
        const float rstd = rsqrtf(var + 1e-5f);
        const float4 gg = *(const float4*)&g[tid * 4];
        const float4 bb = *(const float4*)&bta[tid * 4];
        ushort4 o;
        o.x = f2bf((v.x - mean) * rstd * gg.x + bb.x);
        o.y = f2bf((v.y - mean) * rstd * gg.y + bb.y);
        o.z = f2bf((v.z - mean) * rstd * gg.z + bb.z);
        o.w = f2bf((v.w - mean) * rstd * gg.w + bb.w);
        *(ushort4*)&xn[(size_t)row * 1024 + tid * 4] = o;
    } else {
        const float* in; u16* outT; int N, idx;
        if (bid < 4864) { in = wqkv; outT = wqkvT; N = 3072; idx = bid - 4096; }
        else            { in = wout; outT = woutT; N = 1024; idx = bid - 4864; }
        const int K = 1024;
        const int k0 = (idx & 15) * 64, n0 = (idx >> 4) * 64;
        __shared__ u16 tile[64][72];   // [n][k]
        #pragma unroll
        for (int i = 0; i < 4; ++i) {
            int c = tid + i * 256;             // 0..1023
            int kr = c >> 4, nc = (c & 15) * 4;
            float4 v = *(const float4*)&in[(size_t)(k0 + kr) * N + n0 + nc];
            tile[nc + 0][kr] = f2bf(v.x);
            tile[nc + 1][kr] = f2bf(v.y);
            tile[nc + 2][kr] = f2bf(v.z);
            tile[nc + 3][kr] = f2bf(v.w);
        }
        __syncthreads();
        #pragma unroll
        for (int i = 0; i < 4; ++i) {
            int c = tid + i * 256;
            int nr = c >> 4, kc = (c & 15) * 4;
            ushort4 w = *(const ushort4*)&tile[nr][kc];
            *(ushort4*)&outT[(size_t)(n0 + nr) * K + k0 + kc] = w;
        }
    }
}

// ---------------- GEMM: A bf16 [M][K] x Bt bf16 [N][K], tile 128 x BN ------
// XCD-aware block swizzle (grid %8==0): contiguous work chunks per XCD so
// neighbor blocks' shared A/B panels hit the XCD-private L2.
// EPI==0 (BN=128): scatter epilogue -> Q(*0.125)/K/V bf16 [b][h][2048][64]
// EPI==1: plain fp32 store -> Cf [M][N].
template <int EPI, int BN>
__global__ __launch_bounds__(256) void gemm_bf16_k(
    const u16* __restrict__ A, const u16* __restrict__ Bt,
    int M, int N, int K,
    float* __restrict__ Cf,
    u16* __restrict__ Qo, u16* __restrict__ Ko, u16* __restrict__ Vo)
{
    constexpr int NF = BN / 32;              // B-fragments per wave (4 or 2)
    __shared__ u16 lds[2][4096 + BN * 32];   // A tile [128][32] @0, B tile [BN][32] @4096
    const int tid = threadIdx.x;
    const int lane = tid & 63, w = tid >> 6;
    const int l15 = lane & 15, l4 = lane >> 4;
    const int wm = w & 1, wn = w >> 1;       // 2x2 wave grid: 64 x BN/2 each

    // XCD swizzle: orig%8 = XCD -> give each XCD a contiguous work chunk
    const int nwg = gridDim.x * gridDim.y;
    int lin = blockIdx.y * gridDim.x + blockIdx.x;
    lin = (lin & 7) * (nwg >> 3) + (lin >> 3);
    const int bx = lin % gridDim.x, by = lin / gridDim.x;
    const int n0 = bx * BN, m0 = by * 128;

    auto stage = [&](int buf, int kt) {
        const u16* Ab = A + (size_t)m0 * K + kt * 32;
        const u16* Bb = Bt + (size_t)n0 * K + kt * 32;
        #pragma unroll
        for (int i = 0; i < 2; ++i) {        // A: 512 chunks of 16B
            int c = tid + (i << 8);
            int r = c >> 2, ke = (c & 3) * 8;
            __builtin_amdgcn_global_load_lds(
                (const __attribute__((address_space(1))) void*)(Ab + (size_t)r * K + ke),
                (__attribute__((address_space(3))) void*)(&lds[buf][0] + c * 8), 16, 0, 0);
        }
        #pragma unroll
        for (int i = 0; i < BN / 64; ++i) {  // B: BN*4 chunks of 16B
            int c = tid + (i << 8);
            int r = c >> 2, ke = (c & 3) * 8;
            __builtin_amdgcn_global_load_lds(
                (const __attribute__((address_space(1))) void*)(Bb + (size_t)r * K + ke),
                (__attribute__((address_space(3))) void*)(&lds[buf][4096] + c * 8), 16, 0, 0);
        }
    };

    f32x4 acc[4][NF];
    #pragma unroll
    for (int mf = 0; mf < 4; ++mf)
        #pragma unroll
        for (int nf = 0; nf < NF; ++nf)
            acc[mf][nf] = f32x4{0.f, 0.f, 0.f, 0.f};

    const int NT = K >> 5;
    stage(0, 0);
    __syncthreads();
    for (int kt = 0; kt < NT; ++kt) {
        const int buf = kt & 1;
        if (kt + 1 < NT) stage(buf ^ 1, kt + 1);
        const u16* Ab = &lds[buf][0];
        const u16* Bb = &lds[buf][4096];
        bf16x8 af[4], bfv[NF];
        #pragma unroll
        for (int mf = 0; mf < 4; ++mf)
            af[mf] = *(const bf16x8*)(Ab + (wm * 64 + mf * 16 + l15) * 32 + l4 * 8);
        #pragma unroll
        for (int nf = 0; nf < NF; ++nf)
            bfv[nf] = *(const bf16x8*)(Bb + (wn * (BN / 2) + nf * 16 + l15) * 32 + l4 * 8);
        #pragma unroll
        for (int mf = 0; mf < 4; ++mf)
            #pragma unroll
            for (int nf = 0; nf < NF; ++nf)
                acc[mf][nf] = __builtin_amdgcn_mfma_f32_16x16x32_bf16(
                    af[mf], bfv[nf], acc[mf][nf], 0, 0, 0);
        __syncthreads();
    }

    #pragma unroll
    for (int mf = 0; mf < 4; ++mf) {
        #pragma unroll
        for (int nf = 0; nf < NF; ++nf) {
            #pragma unroll
            for (int r = 0; r < 4; ++r) {
                const int row = m0 + wm * 64 + mf * 16 + l4 * 4 + r;
                const int col = n0 + wn * (BN / 2) + nf * 16 + l15;
                const float v = acc[mf][nf][r];
                if (EPI == 1) {
                    Cf[(size_t)row * N + col] = v;
                } else {
                    const int t = col >> 10, rem = col & 1023;
                    const int h = rem >> 6, d = rem & 63;
                    const int b = row >> 11, nn = row & 2047;
                    const size_t idx = ((size_t)((b * 16 + h) * 2048 + nn)) * 64 + d;
                    if (t == 0)      Qo[idx] = f2bf(v * 0.125f);
                    else if (t == 1) Ko[idx] = f2bf(v);
                    else             Vo[idx] = f2bf(v);
                }
            }
        }
    }
}

// ---------------- Flash attention, causal, +bias ----------------
// 512 threads = 8 waves, 128 q-rows/block (16/wave), KV tiles of 64.
// Raw s_barrier (lgkmcnt-only drain): K/V/bias global loads land in
// REGISTERS and are same-wave consumed, so no vmcnt(0) drain is needed
// at the barrier. Bias double-buffered in registers.
// NEW (R16): V is consumed ROW-major (same coalesced load as K) and
// transposed during the LDS publish (8 scalar u16 ds_writes/thread into
// V_lds[d][kv]) — eliminates the separate transpose_v kernel and its
// 32 MB HBM round-trip. V_lds stride 66 u16 (odd word stride) keeps the
// transposing writes ~4-way and the b128 reads ~2-way bank-conflicted.
__global__ __launch_bounds__(512, 2) void attn_kernel(
    const u16* __restrict__ Q, const u16* __restrict__ Kmat,
    const u16* __restrict__ Vmat, const float* __restrict__ bias,
    u16* __restrict__ att)
{
    const int hb = blockIdx.x;               // h*2 + b : batch-pairs adjacent
    const int h = hb >> 1, b = hb & 1;
    const int bh = b * 16 + h;
    const int y = blockIdx.y;
    const int qb = (y < 8) ? y : 23 - y;      // blocks L and L+256 (same CU) sum qb=15
    const int q0 = qb << 7;                   // 128 q-rows per block
    const int tid = threadIdx.x;
    const int w = tid >> 6, lane = tid & 63;
    const int l15 = lane & 15, l4 = lane >> 4;

    __shared__ u16 K_lds[2][64][72];        // [buf][kv][d]
    __shared__ u16 V_lds[2][64][66];        // [buf][d][kv]  (transposed at publish)
    __shared__ u16 P_lds[8][16][72];        // per-wave [qrow][kv]

    const int qrow_a = q0 + w * 16 + l15;    // A-frag row
    bf16x8 qa[2];
    #pragma unroll
    for (int ks = 0; ks < 2; ++ks)
        qa[ks] = *(const bf16x8*)(Q + ((size_t)bh * 2048 + qrow_a) * 64 + ks * 32 + l4 * 8);

    f32x4 acc_o[4];
    #pragma unroll
    for (int nf = 0; nf < 4; ++nf) acc_o[nf] = f32x4{0.f, 0.f, 0.f, 0.f};
    float m_r[4], l_r[4];
    #pragma unroll
    for (int r = 0; r < 4; ++r) { m_r[r] = -INFINITY; l_r[r] = 0.f; }

    const int qrow_c = q0 + w * 16 + l4 * 4;  // C-frag row base
    const int qlim = q0 + w * 16 + 15;        // last q-row this wave owns
    const float* biasrow = bias + (size_t)h * 2048 * 2048;

    // register staging for next K/V tile: 512 threads cover one 64x64 tile
    // each; K and V now use the SAME row-major coalesced load pattern.
    const int rr_s = tid >> 3, pp_s = (tid & 7) * 8;
    int4 kreg, vreg;
    auto issue_loads = [&](int j0n) {
        kreg = *(const int4*)&Kmat[((size_t)bh * 2048 + j0n + rr_s) * 64 + pp_s];
        vreg = *(const int4*)&Vmat[((size_t)bh * 2048 + j0n + rr_s) * 64 + pp_s];
    };
    auto load_bias = [&](int j0n, float (&dst)[4][4]) {
        #pragma unroll
        for (int nf = 0; nf < 4; ++nf)
            #pragma unroll
            for (int r = 0; r < 4; ++r)
                dst[nf][r] = biasrow[(size_t)(qrow_c + r) * 2048 + j0n + nf * 16 + l15];
    };

    const int NT = 2 * qb + 2;               // always even
    float bregA[4][4], bregB[4][4];

    // prologue: K/V tile 0 and bias tile 0 in flight
    issue_loads(0);
    load_bias(0, bregA);

    auto tile_step = [&](int jt, float (&bcur)[4][4], float (&bnext)[4][4]) {
        const int j0 = jt << 6;
        const int buf = jt & 1;
        // publish THIS tile's staged K/V (vmcnt wait here covers 1 full tile
        // except jt=0), then fire next tile's loads immediately.
        // K: straight b128 write. V: transposing scalar writes (d=pp_s+j,
        // kv=rr_s) -> V_lds[d][kv].
        *(int4*)&K_lds[buf][rr_s][pp_s] = kreg;
        {
            union { int4 v; u16 u[8]; } uu; uu.v = vreg;
            #pragma unroll
            for (int j = 0; j < 8; ++j)
                V_lds[buf][pp_s + j][rr_s] = uu.u[j];
        }
        if (jt + 1 < NT) {
            issue_loads((jt + 1) << 6);
            if (((jt + 1) << 6) <= qlim) load_bias((jt + 1) << 6, bnext);
        }
        // raw barrier: drain only LDS (ds_writes must be visible); global
        // loads stay in flight across the barrier.
        __builtin_amdgcn_sched_barrier(0);
        asm volatile("s_waitcnt lgkmcnt(0)" ::: "memory");
        __builtin_amdgcn_s_barrier();
        __builtin_amdgcn_sched_barrier(0);

        if (j0 <= qlim) {                     // wave not fully masked
            // QK^T
            f32x4 s[4];
            #pragma unroll
            for (int nf = 0; nf < 4; ++nf) s[nf] = f32x4{0.f, 0.f, 0.f, 0.f};
            __builtin_amdgcn_s_setprio(1);
            #pragma unroll
            for (int ks = 0; ks < 2; ++ks)
                #pragma unroll
                for (int nf = 0; nf < 4; ++nf) {
                    bf16x8 kb = *(const bf16x8*)&K_lds[buf][nf * 16 + l15][ks * 32 + l4 * 8];
                    s[nf] = __builtin_amdgcn_mfma_f32_16x16x32_bf16(qa[ks], kb, s[nf], 0, 0, 0);
                }
            __builtin_amdgcn_s_setprio(0);

            // p = s + bias (bcur loaded one tile ago), causal mask on boundary
            float p[4][4];
            if (j0 + 63 > q0 + w * 16) {
                #pragma unroll
                for (int nf = 0; nf < 4; ++nf) {
                    const int col = j0 + nf * 16 + l15;
                    #pragma unroll
                    for (int r = 0; r < 4; ++r) {
                        const int qr = qrow_c + r;
                        float v = s[nf][r] + bcur[nf][r];
                        p[nf][r] = (col > qr) ? -1e30f : v;
                    }
                }
            } else {
                #pragma unroll
                for (int nf = 0; nf < 4; ++nf)
                    #pragma unroll
                    for (int r = 0; r < 4; ++r)
                        p[nf][r] = s[nf][r] + bcur[nf][r];
            }

            // lane-local row max; defer-max: skip reduce+rescale unless needed
            float mt[4];
            #pragma unroll
            for (int r = 0; r < 4; ++r)
                mt[r] = fmaxf(fmaxf(p[0][r], p[1][r]), fmaxf(p[2][r], p[3][r]));
            int need = 0;
            #pragma unroll
            for (int r = 0; r < 4; ++r) need |= (mt[r] > m_r[r] + 8.0f);
            if (__any(need)) {
                #pragma unroll
                for (int off = 1; off < 16; off <<= 1)
                    #pragma unroll
                    for (int r = 0; r < 4; ++r) mt[r] = fmaxf(mt[r], __shfl_xor(mt[r], off));
                #pragma unroll
                for (int r = 0; r < 4; ++r) {
                    const float mn = fmaxf(m_r[r], mt[r]);
                    const float alpha = __expf(m_r[r] - mn);
                    m_r[r] = mn;
                    l_r[r] *= alpha;
                    #pragma unroll
                    for (int nf = 0; nf < 4; ++nf) acc_o[nf][r] *= alpha;
                }
            }

            // exp + inline P->LDS write + row-sum (no extra pv_ array)
            float ps[4] = {0.f, 0.f, 0.f, 0.f};
            #pragma unroll
            for (int nf = 0; nf < 4; ++nf)
                #pragma unroll
                for (int r = 0; r < 4; ++r) {
                    const float e = __expf(p[nf][r] - m_r[r]);
                    ps[r] += e;
                    P_lds[w][l4 * 4 + r][nf * 16 + l15] = f2bf(e);
                }
            #pragma unroll
            for (int off = 1; off < 16; off <<= 1)
                #pragma unroll
                for (int r = 0; r < 4; ++r) ps[r] += __shfl_xor(ps[r], off);
            #pragma unroll
            for (int r = 0; r < 4; ++r) l_r[r] += ps[r];

            // PV (P read back from LDS; same-wave lgkm dependency)
            __builtin_amdgcn_s_setprio(1);
            #pragma unroll
            for (int ks = 0; ks < 2; ++ks) {
                bf16x8 pa = *(const bf16x8*)&P_lds[w][l15][ks * 32 + l4 * 8];
                #pragma unroll
                for (int nf = 0; nf < 4; ++nf) {
                    bf16x8 vb = *(const bf16x8*)&V_lds[buf][nf * 16 + l15][ks * 32 + l4 * 8];
                    acc_o[nf] = __builtin_amdgcn_mfma_f32_16x16x32_bf16(pa, vb, acc_o[nf], 0, 0, 0);
                }
            }
            __builtin_amdgcn_s_setprio(0);
        }
    };

    for (int jt = 0; jt < NT; jt += 2) {
        tile_step(jt,     bregA, bregB);
        tile_step(jt + 1, bregB, bregA);
    }

    #pragma unroll
    for (int nf = 0; nf < 4; ++nf)
        #pragma unroll
        for (int r = 0; r < 4; ++r) {
            const int qr = qrow_c + r;
            const float o = acc_o[nf][r] / l_r[r];
            att[((size_t)b * 2048 + qr) * 1024 + h * 64 + nf * 16 + l15] = f2bf(o);
        }
}

extern "C" void kernel_launch(void* const* d_in, const int* in_sizes, int n_in,
                              void* d_out, int out_size, void* d_ws, size_t ws_size,
                              hipStream_t stream) {
    const float* x     = (const float*)d_in[0];
    const float* bias  = (const float*)d_in[1];
    const float* gamma = (const float*)d_in[2];
    const float* beta_ = (const float*)d_in[3];
    const float* wqkv  = (const float*)d_in[4];
    const float* wout  = (const float*)d_in[5];
    float* out = (float*)d_out;

    char* ws = (char*)d_ws;
    u16* xn     = (u16*)(ws + 0);          // 8 MB  (also reused as att later)
    u16* wqkvT  = (u16*)(ws + 8388608);    // 6 MB
    u16* woutT  = (u16*)(ws + 14680064);   // 2 MB
    u16* Qb     = (u16*)(ws + 16777216);   // 8 MB
    u16* Kb     = (u16*)(ws + 25165824);   // 8 MB
    u16* Vb     = (u16*)(ws + 33554432);   // 8 MB
    u16* attb   = xn;                      // xn dead after QKV GEMM

    prep_kernel<<<5120, 256, 0, stream>>>(x, gamma, beta_, xn, wqkv, wqkvT, wout, woutT);
    gemm_bf16_k<0, 128><<<dim3(24, 32), 256, 0, stream>>>(xn, wqkvT, 4096, 3072, 1024,
                                                          nullptr, Qb, Kb, Vb);
    attn_kernel<<<dim3(32, 16), 512, 0, stream>>>(Qb, Kb, Vb, bias, attb);
    gemm_bf16_k<1, 64><<<dim3(16, 32), 256, 0, stream>>>(attb, woutT, 4096, 1024, 1024,
                                                         out, nullptr, nullptr, nullptr);
}

// Round 17
// 137.644 us; speedup vs baseline: 1.0365x; 1.0365x over previous
//
#include <hip/hip_runtime.h>
#include <hip/hip_bf16.h>
#include <math.h>

typedef unsigned short u16;
typedef __attribute__((ext_vector_type(8))) __bf16 bf16x8;
typedef __attribute__((ext_vector_type(4))) float f32x4;

static __device__ __forceinline__ u16 f2bf(float f) {
    unsigned int u = __builtin_bit_cast(unsigned int, f);
    u += 0x7fffu + ((u >> 16) & 1u);   // RNE
    return (u16)(u >> 16);
}

// ---------------- Fused prep: LN + w_qkv transpose + w_out transpose ----------
// blocks [0,4096)    : LayerNorm row -> xn bf16
// blocks [4096,4864) : wqkv fp32 [1024][3072] -> wqkvT bf16 [3072][1024]
// blocks [4864,5120) : wout fp32 [1024][1024] -> woutT bf16 [1024][1024]
__global__ __launch_bounds__(256) void prep_kernel(
    const float* __restrict__ x, const float* __restrict__ g,
    const float* __restrict__ bta, u16* __restrict__ xn,
    const float* __restrict__ wqkv, u16* __restrict__ wqkvT,
    const float* __restrict__ wout, u16* __restrict__ woutT)
{
    const int bid = blockIdx.x;
    const int tid = threadIdx.x;
    if (bid < 4096) {
        const int row = bid;
        const float4 v = *(const float4*)&x[(size_t)row * 1024 + tid * 4];
        float s  = v.x + v.y + v.z + v.w;
        float s2 = v.x * v.x + v.y * v.y + v.z * v.z + v.w * v.w;
        #pragma unroll
        for (int off = 32; off; off >>= 1) {
            s  += __shfl_xor(s,  off);
            s2 += __shfl_xor(s2, off);
        }
        __shared__ float red[8];
        if ((tid & 63) == 0) { red[tid >> 6] = s; red[4 + (tid >> 6)] = s2; }
        __syncthreads();
        s  = red[0] + red[1] + red[2] + red[3];
        s2 = red[4] + red[5] + red[6] + red[7];
        const float mean = s * (1.0f / 1024.0f);
        const float var  = s2 * (1.0f / 1024.0f) - mean * mean;
        const float rstd = rsqrtf(var + 1e-5f);
        const float4 gg = *(const float4*)&g[tid * 4];
        const float4 bb = *(const float4*)&bta[tid * 4];
        ushort4 o;
        o.x = f2bf((v.x - mean) * rstd * gg.x + bb.x);
        o.y = f2bf((v.y - mean) * rstd * gg.y + bb.y);
        o.z = f2bf((v.z - mean) * rstd * gg.z + bb.z);
        o.w = f2bf((v.w - mean) * rstd * gg.w + bb.w);
        *(ushort4*)&xn[(size_t)row * 1024 + tid * 4] = o;
    } else {
        const float* in; u16* outT; int N, idx;
        if (bid < 4864) { in = wqkv; outT = wqkvT; N = 3072; idx = bid - 4096; }
        else            { in = wout; outT = woutT; N = 1024; idx = bid - 4864; }
        const int K = 1024;
        const int k0 = (idx & 15) * 64, n0 = (idx >> 4) * 64;
        __shared__ u16 tile[64][72];   // [n][k]
        #pragma unroll
        for (int i = 0; i < 4; ++i) {
            int c = tid + i * 256;             // 0..1023
            int kr = c >> 4, nc = (c & 15) * 4;
            float4 v = *(const float4*)&in[(size_t)(k0 + kr) * N + n0 + nc];
            tile[nc + 0][kr] = f2bf(v.x);
            tile[nc + 1][kr] = f2bf(v.y);
            tile[nc + 2][kr] = f2bf(v.z);
            tile[nc + 3][kr] = f2bf(v.w);
        }
        __syncthreads();
        #pragma unroll
        for (int i = 0; i < 4; ++i) {
            int c = tid + i * 256;
            int nr = c >> 4, kc = (c & 15) * 4;
            ushort4 w = *(const ushort4*)&tile[nr][kc];
            *(ushort4*)&outT[(size_t)(n0 + nr) * K + k0 + kc] = w;
        }
    }
}

// ------- V transpose: V bf16 [bh][2048][64] -> Vt bf16 [bh][64][2048] -------
__global__ __launch_bounds__(256) void transpose_v_kernel(
    const u16* __restrict__ V, u16* __restrict__ Vt)
{
    const int bh = blockIdx.y;
    const int n0 = blockIdx.x * 64;
    const int tid = threadIdx.x;
    __shared__ u16 t[64][72];   // [d][n_local]
    #pragma unroll
    for (int i = 0; i < 2; ++i) {
        int c = tid + (i << 8);            // 0..511
        int nr = c >> 3, dc = (c & 7) * 8;
        int4 v4 = *(const int4*)&V[((size_t)bh * 2048 + n0 + nr) * 64 + dc];
        union { int4 v; u16 u[8]; } uu; uu.v = v4;
        #pragma unroll
        for (int j = 0; j < 8; ++j) t[dc + j][nr] = uu.u[j];
    }
    __syncthreads();
    #pragma unroll
    for (int i = 0; i < 2; ++i) {
        int c = tid + (i << 8);
        int d = c >> 3, nn = (c & 7) * 8;
        int4 v4 = *(const int4*)&t[d][nn];
        *(int4*)&Vt[((size_t)bh * 64 + d) * 2048 + n0 + nn] = v4;
    }
}

// ---------------- GEMM: A bf16 [M][K] x Bt bf16 [N][K], tile 128 x BN ------
// XCD-aware block swizzle (grid %8==0): contiguous work chunks per XCD so
// neighbor blocks' shared A/B panels hit the XCD-private L2.
// EPI==0 (BN=128): scatter epilogue -> Q(*0.125)/K/V bf16 [b][h][2048][64]
// EPI==1: plain fp32 store -> Cf [M][N].
template <int EPI, int BN>
__global__ __launch_bounds__(256) void gemm_bf16_k(
    const u16* __restrict__ A, const u16* __restrict__ Bt,
    int M, int N, int K,
    float* __restrict__ Cf,
    u16* __restrict__ Qo, u16* __restrict__ Ko, u16* __restrict__ Vo)
{
    constexpr int NF = BN / 32;              // B-fragments per wave (4 or 2)
    __shared__ u16 lds[2][4096 + BN * 32];   // A tile [128][32] @0, B tile [BN][32] @4096
    const int tid = threadIdx.x;
    const int lane = tid & 63, w = tid >> 6;
    const int l15 = lane & 15, l4 = lane >> 4;
    const int wm = w & 1, wn = w >> 1;       // 2x2 wave grid: 64 x BN/2 each

    // XCD swizzle: orig%8 = XCD -> give each XCD a contiguous work chunk
    const int nwg = gridDim.x * gridDim.y;
    int lin = blockIdx.y * gridDim.x + blockIdx.x;
    lin = (lin & 7) * (nwg >> 3) + (lin >> 3);
    const int bx = lin % gridDim.x, by = lin / gridDim.x;
    const int n0 = bx * BN, m0 = by * 128;

    auto stage = [&](int buf, int kt) {
        const u16* Ab = A + (size_t)m0 * K + kt * 32;
        const u16* Bb = Bt + (size_t)n0 * K + kt * 32;
        #pragma unroll
        for (int i = 0; i < 2; ++i) {        // A: 512 chunks of 16B
            int c = tid + (i << 8);
            int r = c >> 2, ke = (c & 3) * 8;
            __builtin_amdgcn_global_load_lds(
                (const __attribute__((address_space(1))) void*)(Ab + (size_t)r * K + ke),
                (__attribute__((address_space(3))) void*)(&lds[buf][0] + c * 8), 16, 0, 0);
        }
        #pragma unroll
        for (int i = 0; i < BN / 64; ++i) {  // B: BN*4 chunks of 16B
            int c = tid + (i << 8);
            int r = c >> 2, ke = (c & 3) * 8;
            __builtin_amdgcn_global_load_lds(
                (const __attribute__((address_space(1))) void*)(Bb + (size_t)r * K + ke),
                (__attribute__((address_space(3))) void*)(&lds[buf][4096] + c * 8), 16, 0, 0);
        }
    };

    f32x4 acc[4][NF];
    #pragma unroll
    for (int mf = 0; mf < 4; ++mf)
        #pragma unroll
        for (int nf = 0; nf < NF; ++nf)
            acc[mf][nf] = f32x4{0.f, 0.f, 0.f, 0.f};

    const int NT = K >> 5;
    stage(0, 0);
    __syncthreads();
    for (int kt = 0; kt < NT; ++kt) {
        const int buf = kt & 1;
        if (kt + 1 < NT) stage(buf ^ 1, kt + 1);
        const u16* Ab = &lds[buf][0];
        const u16* Bb = &lds[buf][4096];
        bf16x8 af[4], bfv[NF];
        #pragma unroll
        for (int mf = 0; mf < 4; ++mf)
            af[mf] = *(const bf16x8*)(Ab + (wm * 64 + mf * 16 + l15) * 32 + l4 * 8);
        #pragma unroll
        for (int nf = 0; nf < NF; ++nf)
            bfv[nf] = *(const bf16x8*)(Bb + (wn * (BN / 2) + nf * 16 + l15) * 32 + l4 * 8);
        #pragma unroll
        for (int mf = 0; mf < 4; ++mf)
            #pragma unroll
            for (int nf = 0; nf < NF; ++nf)
                acc[mf][nf] = __builtin_amdgcn_mfma_f32_16x16x32_bf16(
                    af[mf], bfv[nf], acc[mf][nf], 0, 0, 0);
        __syncthreads();
    }

    #pragma unroll
    for (int mf = 0; mf < 4; ++mf) {
        #pragma unroll
        for (int nf = 0; nf < NF; ++nf) {
            #pragma unroll
            for (int r = 0; r < 4; ++r) {
                const int row = m0 + wm * 64 + mf * 16 + l4 * 4 + r;
                const int col = n0 + wn * (BN / 2) + nf * 16 + l15;
                const float v = acc[mf][nf][r];
                if (EPI == 1) {
                    Cf[(size_t)row * N + col] = v;
                } else {
                    const int t = col >> 10, rem = col & 1023;
                    const int h = rem >> 6, d = rem & 63;
                    const int b = row >> 11, nn = row & 2047;
                    const size_t idx = ((size_t)((b * 16 + h) * 2048 + nn)) * 64 + d;
                    if (t == 0)      Qo[idx] = f2bf(v * 0.125f);
                    else if (t == 1) Ko[idx] = f2bf(v);
                    else             Vo[idx] = f2bf(v);
                }
            }
        }
    }
}

// ---------------- Flash attention, causal, +bias ----------------
// 512 threads = 8 waves, 128 q-rows/block (16/wave), KV tiles of 64.
// Raw s_barrier (lgkmcnt-only drain): K/V/bias global loads land in
// REGISTERS and are same-wave consumed, so no vmcnt(0) drain is needed
// at the barrier. Bias double-buffered in registers (1-deep; 2-deep
// regressed in R14).
// R17: blockIdx.x = b*16+h (was h*2+b) — the two batch-blocks that read
// the IDENTICAL bias slice are now 16 apart in blockIdx.x, so x%8 (their
// XCD) matches: the pair shares one XCD-private L2 and the second block's
// bias reads hit L2 instead of re-fetching from HBM.
__global__ __launch_bounds__(512, 2) void attn_kernel(
    const u16* __restrict__ Q, const u16* __restrict__ Kmat,
    const u16* __restrict__ Vt, const float* __restrict__ bias,
    u16* __restrict__ att)
{
    const int hb = blockIdx.x;
    const int h = hb & 15, b = hb >> 4;       // pair (b=0,1) of head h: same XCD
    const int bh = b * 16 + h;
    const int y = blockIdx.y;
    const int qb = (y < 8) ? y : 23 - y;      // blocks L and L+256 (same CU) sum qb=15
    const int q0 = qb << 7;                   // 128 q-rows per block
    const int tid = threadIdx.x;
    const int w = tid >> 6, lane = tid & 63;
    const int l15 = lane & 15, l4 = lane >> 4;

    __shared__ u16 K_lds[2][64][72];        // [buf][kv][d]
    __shared__ u16 V_lds[2][64][72];        // [buf][d][kv]  (from Vt)
    __shared__ u16 P_lds[8][16][72];        // per-wave [qrow][kv]

    const int qrow_a = q0 + w * 16 + l15;    // A-frag row
    bf16x8 qa[2];
    #pragma unroll
    for (int ks = 0; ks < 2; ++ks)
        qa[ks] = *(const bf16x8*)(Q + ((size_t)bh * 2048 + qrow_a) * 64 + ks * 32 + l4 * 8);

    f32x4 acc_o[4];
    #pragma unroll
    for (int nf = 0; nf < 4; ++nf) acc_o[nf] = f32x4{0.f, 0.f, 0.f, 0.f};
    float m_r[4], l_r[4];
    #pragma unroll
    for (int r = 0; r < 4; ++r) { m_r[r] = -INFINITY; l_r[r] = 0.f; }

    const int qrow_c = q0 + w * 16 + l4 * 4;  // C-frag row base
    const int qlim = q0 + w * 16 + 15;        // last q-row this wave owns
    const float* biasrow = bias + (size_t)h * 2048 * 2048;

    // register staging for next K/V tile: 512 threads cover one 64x64 tile each
    const int rr_s = tid >> 3, pp_s = (tid & 7) * 8;
    int4 kreg, vreg;
    auto issue_loads = [&](int j0n) {
        kreg = *(const int4*)&Kmat[((size_t)bh * 2048 + j0n + rr_s) * 64 + pp_s];
        vreg = *(const int4*)&Vt[((size_t)bh * 64 + rr_s) * 2048 + j0n + pp_s];
    };
    auto load_bias = [&](int j0n, float (&dst)[4][4]) {
        #pragma unroll
        for (int nf = 0; nf < 4; ++nf)
            #pragma unroll
            for (int r = 0; r < 4; ++r)
                dst[nf][r] = biasrow[(size_t)(qrow_c + r) * 2048 + j0n + nf * 16 + l15];
    };

    const int NT = 2 * qb + 2;               // always even
    float bregA[4][4], bregB[4][4];

    // prologue: K/V tile 0 and bias tile 0 in flight
    issue_loads(0);
    load_bias(0, bregA);

    auto tile_step = [&](int jt, float (&bcur)[4][4], float (&bnext)[4][4]) {
        const int j0 = jt << 6;
        const int buf = jt & 1;
        // publish THIS tile's staged K/V (vmcnt wait here covers 1 full tile
        // except jt=0), then fire next tile's loads immediately.
        *(int4*)&K_lds[buf][rr_s][pp_s] = kreg;
        *(int4*)&V_lds[buf][rr_s][pp_s] = vreg;
        if (jt + 1 < NT) {
            issue_loads((jt + 1) << 6);
            if (((jt + 1) << 6) <= qlim) load_bias((jt + 1) << 6, bnext);
        }
        // raw barrier: drain only LDS (ds_writes must be visible); global
        // loads stay in flight across the barrier.
        __builtin_amdgcn_sched_barrier(0);
        asm volatile("s_waitcnt lgkmcnt(0)" ::: "memory");
        __builtin_amdgcn_s_barrier();
        __builtin_amdgcn_sched_barrier(0);

        if (j0 <= qlim) {                     // wave not fully masked
            // QK^T
            f32x4 s[4];
            #pragma unroll
            for (int nf = 0; nf < 4; ++nf) s[nf] = f32x4{0.f, 0.f, 0.f, 0.f};
            __builtin_amdgcn_s_setprio(1);
            #pragma unroll
            for (int ks = 0; ks < 2; ++ks)
                #pragma unroll
                for (int nf = 0; nf < 4; ++nf) {
                    bf16x8 kb = *(const bf16x8*)&K_lds[buf][nf * 16 + l15][ks * 32 + l4 * 8];
                    s[nf] = __builtin_amdgcn_mfma_f32_16x16x32_bf16(qa[ks], kb, s[nf], 0, 0, 0);
                }
            __builtin_amdgcn_s_setprio(0);

            // p = s + bias (bcur loaded one tile ago), causal mask on boundary
            float p[4][4];
            if (j0 + 63 > q0 + w * 16) {
                #pragma unroll
                for (int nf = 0; nf < 4; ++nf) {
                    const int col = j0 + nf * 16 + l15;
                    #pragma unroll
                    for (int r = 0; r < 4; ++r) {
                        const int qr = qrow_c + r;
                        float v = s[nf][r] + bcur[nf][r];
                        p[nf][r] = (col > qr) ? -1e30f : v;
                    }
                }
            } else {
                #pragma unroll
                for (int nf = 0; nf < 4; ++nf)
                    #pragma unroll
                    for (int r = 0; r < 4; ++r)
                        p[nf][r] = s[nf][r] + bcur[nf][r];
            }

            // lane-local row max; defer-max: skip reduce+rescale unless needed
            float mt[4];
            #pragma unroll
            for (int r = 0; r < 4; ++r)
                mt[r] = fmaxf(fmaxf(p[0][r], p[1][r]), fmaxf(p[2][r], p[3][r]));
            int need = 0;
            #pragma unroll
            for (int r = 0; r < 4; ++r) need |= (mt[r] > m_r[r] + 8.0f);
            if (__any(need)) {
                #pragma unroll
                for (int off = 1; off < 16; off <<= 1)
                    #pragma unroll
                    for (int r = 0; r < 4; ++r) mt[r] = fmaxf(mt[r], __shfl_xor(mt[r], off));
                #pragma unroll
                for (int r = 0; r < 4; ++r) {
                    const float mn = fmaxf(m_r[r], mt[r]);
                    const float alpha = __expf(m_r[r] - mn);
                    m_r[r] = mn;
                    l_r[r] *= alpha;
                    #pragma unroll
                    for (int nf = 0; nf < 4; ++nf) acc_o[nf][r] *= alpha;
                }
            }

            // exp + inline P->LDS write + row-sum (no extra pv_ array)
            float ps[4] = {0.f, 0.f, 0.f, 0.f};
            #pragma unroll
            for (int nf = 0; nf < 4; ++nf)
                #pragma unroll
                for (int r = 0; r < 4; ++r) {
                    const float e = __expf(p[nf][r] - m_r[r]);
                    ps[r] += e;
                    P_lds[w][l4 * 4 + r][nf * 16 + l15] = f2bf(e);
                }
            #pragma unroll
            for (int off = 1; off < 16; off <<= 1)
                #pragma unroll
                for (int r = 0; r < 4; ++r) ps[r] += __shfl_xor(ps[r], off);
            #pragma unroll
            for (int r = 0; r < 4; ++r) l_r[r] += ps[r];

            // PV (P read back from LDS; same-wave lgkm dependency)
            __builtin_amdgcn_s_setprio(1);
            #pragma unroll
            for (int ks = 0; ks < 2; ++ks) {
                bf16x8 pa = *(const bf16x8*)&P_lds[w][l15][ks * 32 + l4 * 8];
                #pragma unroll
                for (int nf = 0; nf < 4; ++nf) {
                    bf16x8 vb = *(const bf16x8*)&V_lds[buf][nf * 16 + l15][ks * 32 + l4 * 8];
                    acc_o[nf] = __builtin_amdgcn_mfma_f32_16x16x32_bf16(pa, vb, acc_o[nf], 0, 0, 0);
                }
            }
            __builtin_amdgcn_s_setprio(0);
        }
    };

    for (int jt = 0; jt < NT; jt += 2) {
        tile_step(jt,     bregA, bregB);
        tile_step(jt + 1, bregB, bregA);
    }

    #pragma unroll
    for (int nf = 0; nf < 4; ++nf)
        #pragma unroll
        for (int r = 0; r < 4; ++r) {
            const int qr = qrow_c + r;
            const float o = acc_o[nf][r] / l_r[r];
            att[((size_t)b * 2048 + qr) * 1024 + h * 64 + nf * 16 + l15] = f2bf(o);
        }
}

extern "C" void kernel_launch(void* const* d_in, const int* in_sizes, int n_in,
                              void* d_out, int out_size, void* d_ws, size_t ws_size,
                              hipStream_t stream) {
    const float* x     = (const float*)d_in[0];
    const float* bias  = (const float*)d_in[1];
    const float* gamma = (const float*)d_in[2];
    const float* beta_ = (const float*)d_in[3];
    const float* wqkv  = (const float*)d_in[4];
    const float* wout  = (const float*)d_in[5];
    float* out = (float*)d_out;

    char* ws = (char*)d_ws;
    u16* xn     = (u16*)(ws + 0);          // 8 MB  (also reused as att later)
    u16* wqkvT  = (u16*)(ws + 8388608);    // 6 MB
    u16* woutT  = (u16*)(ws + 14680064);   // 2 MB
    u16* Qb     = (u16*)(ws + 16777216);   // 8 MB
    u16* Kb     = (u16*)(ws + 25165824);   // 8 MB
    u16* Vb     = (u16*)(ws + 33554432);   // 8 MB
    u16* Vtb    = (u16*)(ws + 41943040);   // 8 MB  (total 48 MB)
    u16* attb   = xn;                      // xn dead after QKV GEMM

    prep_kernel<<<5120, 256, 0, stream>>>(x, gamma, beta_, xn, wqkv, wqkvT, wout, woutT);
    gemm_bf16_k<0, 128><<<dim3(24, 32), 256, 0, stream>>>(xn, wqkvT, 4096, 3072, 1024,
                                                          nullptr, Qb, Kb, Vb);
    transpose_v_kernel<<<dim3(32, 32), 256, 0, stream>>>(Vb, Vtb);
    attn_kernel<<<dim3(32, 16), 512, 0, stream>>>(Qb, Kb, Vtb, bias, attb);
    gemm_bf16_k<1, 64><<<dim3(16, 32), 256, 0, stream>>>(attb, woutT, 4096, 1024, 1024,
                                                         out, nullptr, nullptr, nullptr);
}

// Round 18
// 131.870 us; speedup vs baseline: 1.0819x; 1.0438x over previous
//
#include <hip/hip_runtime.h>
#include <hip/hip_bf16.h>
#include <math.h>

typedef unsigned short u16;
typedef __attribute__((ext_vector_type(8))) __bf16 bf16x8;
typedef __attribute__((ext_vector_type(4))) float f32x4;

static __device__ __forceinline__ u16 f2bf(float f) {
    unsigned int u = __builtin_bit_cast(unsigned int, f);
    u += 0x7fffu + ((u >> 16) & 1u);   // RNE
    return (u16)(u >> 16);
}

// ---------------- Fused prep: LN + w_qkv transpose + w_out transpose ----------
// blocks [0,4096)    : LayerNorm row -> xn bf16
// blocks [4096,4864) : wqkv fp32 [1024][3072] -> wqkvT bf16 [3072][1024]
// blocks [4864,5120) : wout fp32 [1024][1024] -> woutT bf16 [1024][1024]
__global__ __launch_bounds__(256) void prep_kernel(
    const float* __restrict__ x, const float* __restrict__ g,
    const float* __restrict__ bta, u16* __restrict__ xn,
    const float* __restrict__ wqkv, u16* __restrict__ wqkvT,
    const float* __restrict__ wout, u16* __restrict__ woutT)
{
    const int bid = blockIdx.x;
    const int tid = threadIdx.x;
    if (bid < 4096) {
        const int row = bid;
        const float4 v = *(const float4*)&x[(size_t)row * 1024 + tid * 4];
        float s  = v.x + v.y + v.z + v.w;
        float s2 = v.x * v.x + v.y * v.y + v.z * v.z + v.w * v.w;
        #pragma unroll
        for (int off = 32; off; off >>= 1) {
            s  += __shfl_xor(s,  off);
            s2 += __shfl_xor(s2, off);
        }
        __shared__ float red[8];
        if ((tid & 63) == 0) { red[tid >> 6] = s; red[4 + (tid >> 6)] = s2; }
        __syncthreads();
        s  = red[0] + red[1] + red[2] + red[3];
        s2 = red[4] + red[5] + red[6] + red[7];
        const float mean = s * (1.0f / 1024.0f);
        const float var  = s2 * (1.0f / 1024.0f) - mean * mean;
        const float rstd = rsqrtf(var + 1e-5f);
        const float4 gg = *(const float4*)&g[tid * 4];
        const float4 bb = *(const float4*)&bta[tid * 4];
        ushort4 o;
        o.x = f2bf((v.x - mean) * rstd * gg.x + bb.x);
        o.y = f2bf((v.y - mean) * rstd * gg.y + bb.y);
        o.z = f2bf((v.z - mean) * rstd * gg.z + bb.z);
        o.w = f2bf((v.w - mean) * rstd * gg.w + bb.w);
        *(ushort4*)&xn[(size_t)row * 1024 + tid * 4] = o;
    } else {
        const float* in; u16* outT; int N, idx;
        if (bid < 4864) { in = wqkv; outT = wqkvT; N = 3072; idx = bid - 4096; }
        else            { in = wout; outT = woutT; N = 1024; idx = bid - 4864; }
        const int K = 1024;
        const int k0 = (idx & 15) * 64, n0 = (idx >> 4) * 64;
        __shared__ u16 tile[64][72];   // [n][k]
        #pragma unroll
        for (int i = 0; i < 4; ++i) {
            int c = tid + i * 256;             // 0..1023
            int kr = c >> 4, nc = (c & 15) * 4;
            float4 v = *(const float4*)&in[(size_t)(k0 + kr) * N + n0 + nc];
            tile[nc + 0][kr] = f2bf(v.x);
            tile[nc + 1][kr] = f2bf(v.y);
            tile[nc + 2][kr] = f2bf(v.z);
            tile[nc + 3][kr] = f2bf(v.w);
        }
        __syncthreads();
        #pragma unroll
        for (int i = 0; i < 4; ++i) {
            int c = tid + i * 256;
            int nr = c >> 4, kc = (c & 15) * 4;
            ushort4 w = *(const ushort4*)&tile[nr][kc];
            *(ushort4*)&outT[(size_t)(n0 + nr) * K + k0 + kc] = w;
        }
    }
}

// ---------------- GEMM: A bf16 [M][K] x Bt bf16 [N][K], tile 128 x BN ------
// XCD-aware block swizzle (grid %8==0): contiguous work chunks per XCD so
// neighbor blocks' shared A/B panels hit the XCD-private L2.
// EPI==0 (BN=128): scatter epilogue -> Q(*0.125)/K bf16 [b][h][2048][64] and
//                  V^T bf16 [b][h][64][2048] (fused transpose: 4 lanes share
//                  one contiguous 32B run per d -> L2-absorbed)
// EPI==1: plain fp32 store -> Cf [M][N].
template <int EPI, int BN>
__global__ __launch_bounds__(256) void gemm_bf16_k(
    const u16* __restrict__ A, const u16* __restrict__ Bt,
    int M, int N, int K,
    float* __restrict__ Cf,
    u16* __restrict__ Qo, u16* __restrict__ Ko, u16* __restrict__ Vto)
{
    constexpr int NF = BN / 32;              // B-fragments per wave (4 or 2)
    __shared__ u16 lds[2][4096 + BN * 32];   // A tile [128][32] @0, B tile [BN][32] @4096
    const int tid = threadIdx.x;
    const int lane = tid & 63, w = tid >> 6;
    const int l15 = lane & 15, l4 = lane >> 4;
    const int wm = w & 1, wn = w >> 1;       // 2x2 wave grid: 64 x BN/2 each

    // XCD swizzle: orig%8 = XCD -> give each XCD a contiguous work chunk
    const int nwg = gridDim.x * gridDim.y;
    int lin = blockIdx.y * gridDim.x + blockIdx.x;
    lin = (lin & 7) * (nwg >> 3) + (lin >> 3);
    const int bx = lin % gridDim.x, by = lin / gridDim.x;
    const int n0 = bx * BN, m0 = by * 128;

    auto stage = [&](int buf, int kt) {
        const u16* Ab = A + (size_t)m0 * K + kt * 32;
        const u16* Bb = Bt + (size_t)n0 * K + kt * 32;
        #pragma unroll
        for (int i = 0; i < 2; ++i) {        // A: 512 chunks of 16B
            int c = tid + (i << 8);
            int r = c >> 2, ke = (c & 3) * 8;
            __builtin_amdgcn_global_load_lds(
                (const __attribute__((address_space(1))) void*)(Ab + (size_t)r * K + ke),
                (__attribute__((address_space(3))) void*)(&lds[buf][0] + c * 8), 16, 0, 0);
        }
        #pragma unroll
        for (int i = 0; i < BN / 64; ++i) {  // B: BN*4 chunks of 16B
            int c = tid + (i << 8);
            int r = c >> 2, ke = (c & 3) * 8;
            __builtin_amdgcn_global_load_lds(
                (const __attribute__((address_space(1))) void*)(Bb + (size_t)r * K + ke),
                (__attribute__((address_space(3))) void*)(&lds[buf][4096] + c * 8), 16, 0, 0);
        }
    };

    f32x4 acc[4][NF];
    #pragma unroll
    for (int mf = 0; mf < 4; ++mf)
        #pragma unroll
        for (int nf = 0; nf < NF; ++nf)
            acc[mf][nf] = f32x4{0.f, 0.f, 0.f, 0.f};

    const int NT = K >> 5;
    stage(0, 0);
    __syncthreads();
    for (int kt = 0; kt < NT; ++kt) {
        const int buf = kt & 1;
        if (kt + 1 < NT) stage(buf ^ 1, kt + 1);
        const u16* Ab = &lds[buf][0];
        const u16* Bb = &lds[buf][4096];
        bf16x8 af[4], bfv[NF];
        #pragma unroll
        for (int mf = 0; mf < 4; ++mf)
            af[mf] = *(const bf16x8*)(Ab + (wm * 64 + mf * 16 + l15) * 32 + l4 * 8);
        #pragma unroll
        for (int nf = 0; nf < NF; ++nf)
            bfv[nf] = *(const bf16x8*)(Bb + (wn * (BN / 2) + nf * 16 + l15) * 32 + l4 * 8);
        #pragma unroll
        for (int mf = 0; mf < 4; ++mf)
            #pragma unroll
            for (int nf = 0; nf < NF; ++nf)
                acc[mf][nf] = __builtin_amdgcn_mfma_f32_16x16x32_bf16(
                    af[mf], bfv[nf], acc[mf][nf], 0, 0, 0);
        __syncthreads();
    }

    #pragma unroll
    for (int mf = 0; mf < 4; ++mf) {
        #pragma unroll
        for (int nf = 0; nf < NF; ++nf) {
            const int row0 = m0 + wm * 64 + mf * 16 + l4 * 4;   // 4 consecutive rows
            const int col  = n0 + wn * (BN / 2) + nf * 16 + l15;
            if (EPI == 1) {
                #pragma unroll
                for (int r = 0; r < 4; ++r)
                    Cf[(size_t)(row0 + r) * N + col] = acc[mf][nf][r];
            } else {
                const int t = col >> 10, rem = col & 1023;
                const int h = rem >> 6, d = rem & 63;
                const int b0 = row0 >> 11, nn0 = row0 & 2047;   // r never crosses 2048
                if (t == 2) {
                    // V^T fused store: 4 consecutive n for fixed d -> ushort4
                    union { ushort4 v; u16 e[4]; } vv;
                    #pragma unroll
                    for (int r = 0; r < 4; ++r) vv.e[r] = f2bf(acc[mf][nf][r]);
                    *(ushort4*)&Vto[((size_t)((b0 * 16 + h) * 64) + d) * 2048 + nn0] = vv.v;
                } else {
                    #pragma unroll
                    for (int r = 0; r < 4; ++r) {
                        const size_t idx = ((size_t)((b0 * 16 + h) * 2048 + nn0 + r)) * 64 + d;
                        if (t == 0) Qo[idx] = f2bf(acc[mf][nf][r] * 0.125f);
                        else        Ko[idx] = f2bf(acc[mf][nf][r]);
                    }
                }
            }
        }
    }
}

// ---------------- Flash attention, causal, +bias ----------------
// 512 threads = 8 waves, 128 q-rows/block (16/wave), KV tiles of 64.
// Raw s_barrier (lgkmcnt-only drain): K/V/bias global loads land in
// REGISTERS and are same-wave consumed, so no vmcnt(0) drain is needed
// at the barrier. Bias double-buffered in registers (1-deep; 2-deep
// regressed in R14). blockIdx.x = b*16+h so the two batch-blocks reading
// the identical bias slice land on the same XCD (L2 sharing, R17).
__global__ __launch_bounds__(512, 2) void attn_kernel(
    const u16* __restrict__ Q, const u16* __restrict__ Kmat,
    const u16* __restrict__ Vt, const float* __restrict__ bias,
    u16* __restrict__ att)
{
    const int hb = blockIdx.x;
    const int h = hb & 15, b = hb >> 4;       // pair (b=0,1) of head h: same XCD
    const int bh = b * 16 + h;
    const int y = blockIdx.y;
    const int qb = (y < 8) ? y : 23 - y;      // blocks L and L+256 (same CU) sum qb=15
    const int q0 = qb << 7;                   // 128 q-rows per block
    const int tid = threadIdx.x;
    const int w = tid >> 6, lane = tid & 63;
    const int l15 = lane & 15, l4 = lane >> 4;

    __shared__ u16 K_lds[2][64][72];        // [buf][kv][d]
    __shared__ u16 V_lds[2][64][72];        // [buf][d][kv]  (from Vt)
    __shared__ u16 P_lds[8][16][72];        // per-wave [qrow][kv]

    const int qrow_a = q0 + w * 16 + l15;    // A-frag row
    bf16x8 qa[2];
    #pragma unroll
    for (int ks = 0; ks < 2; ++ks)
        qa[ks] = *(const bf16x8*)(Q + ((size_t)bh * 2048 + qrow_a) * 64 + ks * 32 + l4 * 8);

    f32x4 acc_o[4];
    #pragma unroll
    for (int nf = 0; nf < 4; ++nf) acc_o[nf] = f32x4{0.f, 0.f, 0.f, 0.f};
    float m_r[4], l_r[4];
    #pragma unroll
    for (int r = 0; r < 4; ++r) { m_r[r] = -INFINITY; l_r[r] = 0.f; }

    const int qrow_c = q0 + w * 16 + l4 * 4;  // C-frag row base
    const int qlim = q0 + w * 16 + 15;        // last q-row this wave owns
    const float* biasrow = bias + (size_t)h * 2048 * 2048;

    // register staging for next K/V tile: 512 threads cover one 64x64 tile each
    const int rr_s = tid >> 3, pp_s = (tid & 7) * 8;
    int4 kreg, vreg;
    auto issue_loads = [&](int j0n) {
        kreg = *(const int4*)&Kmat[((size_t)bh * 2048 + j0n + rr_s) * 64 + pp_s];
        vreg = *(const int4*)&Vt[((size_t)bh * 64 + rr_s) * 2048 + j0n + pp_s];
    };
    auto load_bias = [&](int j0n, float (&dst)[4][4]) {
        #pragma unroll
        for (int nf = 0; nf < 4; ++nf)
            #pragma unroll
            for (int r = 0; r < 4; ++r)
                dst[nf][r] = biasrow[(size_t)(qrow_c + r) * 2048 + j0n + nf * 16 + l15];
    };

    const int NT = 2 * qb + 2;               // always even
    float bregA[4][4], bregB[4][4];

    // prologue: K/V tile 0 and bias tile 0 in flight
    issue_loads(0);
    load_bias(0, bregA);

    auto tile_step = [&](int jt, float (&bcur)[4][4], float (&bnext)[4][4]) {
        const int j0 = jt << 6;
        const int buf = jt & 1;
        // publish THIS tile's staged K/V (vmcnt wait here covers 1 full tile
        // except jt=0), then fire next tile's loads immediately.
        *(int4*)&K_lds[buf][rr_s][pp_s] = kreg;
        *(int4*)&V_lds[buf][rr_s][pp_s] = vreg;
        if (jt + 1 < NT) {
            issue_loads((jt + 1) << 6);
            if (((jt + 1) << 6) <= qlim) load_bias((jt + 1) << 6, bnext);
        }
        // raw barrier: drain only LDS (ds_writes must be visible); global
        // loads stay in flight across the barrier.
        __builtin_amdgcn_sched_barrier(0);
        asm volatile("s_waitcnt lgkmcnt(0)" ::: "memory");
        __builtin_amdgcn_s_barrier();
        __builtin_amdgcn_sched_barrier(0);

        if (j0 <= qlim) {                     // wave not fully masked
            // QK^T
            f32x4 s[4];
            #pragma unroll
            for (int nf = 0; nf < 4; ++nf) s[nf] = f32x4{0.f, 0.f, 0.f, 0.f};
            __builtin_amdgcn_s_setprio(1);
            #pragma unroll
            for (int ks = 0; ks < 2; ++ks)
                #pragma unroll
                for (int nf = 0; nf < 4; ++nf) {
                    bf16x8 kb = *(const bf16x8*)&K_lds[buf][nf * 16 + l15][ks * 32 + l4 * 8];
                    s[nf] = __builtin_amdgcn_mfma_f32_16x16x32_bf16(qa[ks], kb, s[nf], 0, 0, 0);
                }
            __builtin_amdgcn_s_setprio(0);

            // p = s + bias (bcur loaded one tile ago), causal mask on boundary
            float p[4][4];
            if (j0 + 63 > q0 + w * 16) {
                #pragma unroll
                for (int nf = 0; nf < 4; ++nf) {
                    const int col = j0 + nf * 16 + l15;
                    #pragma unroll
                    for (int r = 0; r < 4; ++r) {
                        const int qr = qrow_c + r;
                        float v = s[nf][r] + bcur[nf][r];
                        p[nf][r] = (col > qr) ? -1e30f : v;
                    }
                }
            } else {
                #pragma unroll
                for (int nf = 0; nf < 4; ++nf)
                    #pragma unroll
                    for (int r = 0; r < 4; ++r)
                        p[nf][r] = s[nf][r] + bcur[nf][r];
            }

            // lane-local row max; defer-max: skip reduce+rescale unless needed
            float mt[4];
            #pragma unroll
            for (int r = 0; r < 4; ++r)
                mt[r] = fmaxf(fmaxf(p[0][r], p[1][r]), fmaxf(p[2][r], p[3][r]));
            int need = 0;
            #pragma unroll
            for (int r = 0; r < 4; ++r) need |= (mt[r] > m_r[r] + 8.0f);
            if (__any(need)) {
                #pragma unroll
                for (int off = 1; off < 16; off <<= 1)
                    #pragma unroll
                    for (int r = 0; r < 4; ++r) mt[r] = fmaxf(mt[r], __shfl_xor(mt[r], off));
                #pragma unroll
                for (int r = 0; r < 4; ++r) {
                    const float mn = fmaxf(m_r[r], mt[r]);
                    const float alpha = __expf(m_r[r] - mn);
                    m_r[r] = mn;
                    l_r[r] *= alpha;
                    #pragma unroll
                    for (int nf = 0; nf < 4; ++nf) acc_o[nf][r] *= alpha;
                }
            }

            // exp + inline P->LDS write + row-sum (no extra pv_ array)
            float ps[4] = {0.f, 0.f, 0.f, 0.f};
            #pragma unroll
            for (int nf = 0; nf < 4; ++nf)
                #pragma unroll
                for (int r = 0; r < 4; ++r) {
                    const float e = __expf(p[nf][r] - m_r[r]);
                    ps[r] += e;
                    P_lds[w][l4 * 4 + r][nf * 16 + l15] = f2bf(e);
                }
            #pragma unroll
            for (int off = 1; off < 16; off <<= 1)
                #pragma unroll
                for (int r = 0; r < 4; ++r) ps[r] += __shfl_xor(ps[r], off);
            #pragma unroll
            for (int r = 0; r < 4; ++r) l_r[r] += ps[r];

            // PV (P read back from LDS; same-wave lgkm dependency)
            __builtin_amdgcn_s_setprio(1);
            #pragma unroll
            for (int ks = 0; ks < 2; ++ks) {
                bf16x8 pa = *(const bf16x8*)&P_lds[w][l15][ks * 32 + l4 * 8];
                #pragma unroll
                for (int nf = 0; nf < 4; ++nf) {
                    bf16x8 vb = *(const bf16x8*)&V_lds[buf][nf * 16 + l15][ks * 32 + l4 * 8];
                    acc_o[nf] = __builtin_amdgcn_mfma_f32_16x16x32_bf16(pa, vb, acc_o[nf], 0, 0, 0);
                }
            }
            __builtin_amdgcn_s_setprio(0);
        }
    };

    for (int jt = 0; jt < NT; jt += 2) {
        tile_step(jt,     bregA, bregB);
        tile_step(jt + 1, bregB, bregA);
    }

    #pragma unroll
    for (int nf = 0; nf < 4; ++nf)
        #pragma unroll
        for (int r = 0; r < 4; ++r) {
            const int qr = qrow_c + r;
            const float o = acc_o[nf][r] / l_r[r];
            att[((size_t)b * 2048 + qr) * 1024 + h * 64 + nf * 16 + l15] = f2bf(o);
        }
}

extern "C" void kernel_launch(void* const* d_in, const int* in_sizes, int n_in,
                              void* d_out, int out_size, void* d_ws, size_t ws_size,
                              hipStream_t stream) {
    const float* x     = (const float*)d_in[0];
    const float* bias  = (const float*)d_in[1];
    const float* gamma = (const float*)d_in[2];
    const float* beta_ = (const float*)d_in[3];
    const float* wqkv  = (const float*)d_in[4];
    const float* wout  = (const float*)d_in[5];
    float* out = (float*)d_out;

    char* ws = (char*)d_ws;
    u16* xn     = (u16*)(ws + 0);          // 8 MB  (also reused as att later)
    u16* wqkvT  = (u16*)(ws + 8388608);    // 6 MB
    u16* woutT  = (u16*)(ws + 14680064);   // 2 MB
    u16* Qb     = (u16*)(ws + 16777216);   // 8 MB
    u16* Kb     = (u16*)(ws + 25165824);   // 8 MB
    u16* Vtb    = (u16*)(ws + 33554432);   // 8 MB  (V^T written by GEMM epilogue)
    u16* attb   = xn;                      // xn dead after QKV GEMM

    prep_kernel<<<5120, 256, 0, stream>>>(x, gamma, beta_, xn, wqkv, wqkvT, wout, woutT);
    gemm_bf16_k<0, 128><<<dim3(24, 32), 256, 0, stream>>>(xn, wqkvT, 4096, 3072, 1024,
                                                          nullptr, Qb, Kb, Vtb);
    attn_kernel<<<dim3(32, 16), 512, 0, stream>>>(Qb, Kb, Vtb, bias, attb);
    gemm_bf16_k<1, 64><<<dim3(16, 32), 256, 0, stream>>>(attb, woutT, 4096, 1024, 1024,
                                                         out, nullptr, nullptr, nullptr);
}